// Round 1
// baseline (1132.272 us; speedup 1.0000x reference)
//
#include <hip/hip_runtime.h>
#include <math.h>

#define BATCH 8
#define SEQL 4096
#define DMODEL 512
#define SDIM 64
#define MROWS (BATCH * SEQL)  // 32768
#define LN_EPS 1e-5f

// ---------- helpers ----------
__device__ __forceinline__ float wave_sum(float v) {
#pragma unroll
  for (int off = 32; off > 0; off >>= 1) v += __shfl_xor(v, off, 64);
  return v;
}

__device__ __forceinline__ unsigned short f2bf(float f) {  // RNE float->bf16
  unsigned int u = __float_as_uint(f);
  u += 0x7fffu + ((u >> 16) & 1u);
  return (unsigned short)(u >> 16);
}

__device__ __forceinline__ float gelu_exact(float v) {
  return 0.5f * v * (1.0f + erff(v * 0.70710678118654752f));
}

// ---------- K1: LayerNorm stats for x (mu, rstd per row) ----------
__global__ void ln_stats_kernel(const float* __restrict__ x, float* __restrict__ mu,
                                float* __restrict__ rstd) {
  int row = blockIdx.x * 4 + (threadIdx.x >> 6);
  int lane = threadIdx.x & 63;
  const float4* xp = (const float4*)(x + (size_t)row * DMODEL);
  float4 a = xp[lane * 2];
  float4 b = xp[lane * 2 + 1];
  float s = a.x + a.y + a.z + a.w + b.x + b.y + b.z + b.w;
  float q = a.x * a.x + a.y * a.y + a.z * a.z + a.w * a.w + b.x * b.x + b.y * b.y +
            b.z * b.z + b.w * b.w;
  s = wave_sum(s);
  q = wave_sum(q);
  if (lane == 0) {
    float m = s * (1.0f / DMODEL);
    float var = q * (1.0f / DMODEL) - m * m;
    mu[row] = m;
    rstd[row] = rsqrtf(var + LN_EPS);
  }
}

// ---------- K2: xB = LN(x) @ B   [32768,512]x[512,64] -> [B,L,S] ----------
__global__ __launch_bounds__(256) void xb_gemm_kernel(
    const float* __restrict__ x, const float* __restrict__ mu, const float* __restrict__ rstd,
    const float* __restrict__ gamma, const float* __restrict__ beta,
    const float* __restrict__ Bm, float* __restrict__ xB) {
  __shared__ float aT[32 * 68];  // [k][row], stride 68 keeps ds_read_b128 16B-aligned
  __shared__ float bT[32 * 64];  // [k][n]
  const int t = threadIdx.x;
  const int m0 = blockIdx.x * 64;
  const int ty = t >> 4, tx = t & 15;
  const int r0 = ty * 4, c0 = tx * 4;
  const int lrow = t >> 2, lseg = t & 3;
  const int bk = t >> 3, bseg = t & 7;
  const float mr = mu[m0 + lrow];
  const float rr = rstd[m0 + lrow];
  float acc[4][4] = {};
  for (int k0 = 0; k0 < DMODEL; k0 += 32) {
    __syncthreads();
    {
      const float* xp = x + (size_t)(m0 + lrow) * DMODEL + k0 + lseg * 8;
      float4 v0 = *(const float4*)xp;
      float4 v1 = *(const float4*)(xp + 4);
      float4 g0 = *(const float4*)(gamma + k0 + lseg * 8);
      float4 g1 = *(const float4*)(gamma + k0 + lseg * 8 + 4);
      float4 e0 = *(const float4*)(beta + k0 + lseg * 8);
      float4 e1 = *(const float4*)(beta + k0 + lseg * 8 + 4);
      const int kb = lseg * 8;
      aT[(kb + 0) * 68 + lrow] = (v0.x - mr) * rr * g0.x + e0.x;
      aT[(kb + 1) * 68 + lrow] = (v0.y - mr) * rr * g0.y + e0.y;
      aT[(kb + 2) * 68 + lrow] = (v0.z - mr) * rr * g0.z + e0.z;
      aT[(kb + 3) * 68 + lrow] = (v0.w - mr) * rr * g0.w + e0.w;
      aT[(kb + 4) * 68 + lrow] = (v1.x - mr) * rr * g1.x + e1.x;
      aT[(kb + 5) * 68 + lrow] = (v1.y - mr) * rr * g1.y + e1.y;
      aT[(kb + 6) * 68 + lrow] = (v1.z - mr) * rr * g1.z + e1.z;
      aT[(kb + 7) * 68 + lrow] = (v1.w - mr) * rr * g1.w + e1.w;
      const float* bp = Bm + (size_t)(k0 + bk) * SDIM + bseg * 8;
      *(float4*)&bT[bk * 64 + bseg * 8] = *(const float4*)bp;
      *(float4*)&bT[bk * 64 + bseg * 8 + 4] = *(const float4*)(bp + 4);
    }
    __syncthreads();
#pragma unroll
    for (int kk = 0; kk < 32; ++kk) {
      float4 av = *(const float4*)&aT[kk * 68 + r0];
      float4 bv = *(const float4*)&bT[kk * 64 + c0];
      float ar[4] = {av.x, av.y, av.z, av.w};
      float br[4] = {bv.x, bv.y, bv.z, bv.w};
#pragma unroll
      for (int i = 0; i < 4; ++i)
#pragma unroll
        for (int j = 0; j < 4; ++j) acc[i][j] += ar[i] * br[j];
    }
  }
#pragma unroll
  for (int i = 0; i < 4; ++i) {
    *(float4*)&xB[(size_t)(m0 + r0 + i) * SDIM + c0] =
        make_float4(acc[i][0], acc[i][1], acc[i][2], acc[i][3]);
  }
}

// ---------- K3a/b/c: exact chunked scan h_t = a*h_{t-1} + x_t over L ----------
__global__ void scan_ends_kernel(const float* __restrict__ xB, const float* __restrict__ logA,
                                 const float* __restrict__ logdt, float* __restrict__ ends) {
  int t = blockIdx.x * 256 + threadIdx.x;  // 32768 threads: (b, chunk, s)
  int s = t & 63;
  int c = (t >> 6) & 63;
  int b = t >> 12;
  float a = expf(-expf(logA[s]) * expf(logdt[0]));
  const float* p = xB + ((size_t)(b * SEQL + c * 64)) * SDIM + s;
  float e = 0.0f;
#pragma unroll
  for (int i = 0; i < 64; ++i) e = a * e + p[(size_t)i * SDIM];
  ends[(b * 64 + c) * 64 + s] = e;
}

__global__ void scan_carry_kernel(const float* __restrict__ ends, const float* __restrict__ logA,
                                  const float* __restrict__ logdt,
                                  float* __restrict__ carries) {
  int t = blockIdx.x * 256 + threadIdx.x;  // 512 threads: (b, s)
  int s = t & 63;
  int b = t >> 6;
  float a = expf(-expf(logA[s]) * expf(logdt[0]));
  float a64 = a;
#pragma unroll
  for (int i = 0; i < 6; ++i) a64 *= a64;  // a^64
  float carry = 0.0f;
  for (int c = 0; c < 64; ++c) {
    carries[(b * 64 + c) * 64 + s] = carry;  // state entering chunk c
    carry = a64 * carry + ends[(b * 64 + c) * 64 + s];
  }
}

__global__ void scan_fix_kernel(const float* __restrict__ logA, const float* __restrict__ logdt,
                                const float* __restrict__ carries, float* __restrict__ xB) {
  int t = blockIdx.x * 256 + threadIdx.x;
  int s = t & 63;
  int c = (t >> 6) & 63;
  int b = t >> 12;
  float a = expf(-expf(logA[s]) * expf(logdt[0]));
  float h = carries[(b * 64 + c) * 64 + s];
  float* p = xB + ((size_t)(b * SEQL + c * 64)) * SDIM + s;
#pragma unroll
  for (int i = 0; i < 64; ++i) {
    h = a * h + p[(size_t)i * SDIM];
    p[(size_t)i * SDIM] = h;  // in-place: hs overwrites xB
  }
}

// ---------- K4: y = hs @ C + xn*D + x  -> d_out ----------
__global__ __launch_bounds__(256) void y_gemm_kernel(
    const float* __restrict__ hs, const float* __restrict__ Cm, const float* __restrict__ x,
    const float* __restrict__ mu, const float* __restrict__ rstd,
    const float* __restrict__ gamma, const float* __restrict__ beta,
    const float* __restrict__ Dv, float* __restrict__ out) {
  __shared__ float aT[64 * 68];
  __shared__ float bT[64 * 64];
  const int t = threadIdx.x;
  const int m0 = blockIdx.y * 64;
  const int n0 = blockIdx.x * 64;
  const int ty = t >> 4, tx = t & 15;
  const int r0 = ty * 4, c0 = tx * 4;
  const int lrow = t >> 2, lseg = t & 3;
  {
    const float* hp = hs + (size_t)(m0 + lrow) * SDIM + lseg * 16;
#pragma unroll
    for (int u = 0; u < 4; ++u) {
      float4 v = *(const float4*)(hp + u * 4);
      int kb = lseg * 16 + u * 4;
      aT[(kb + 0) * 68 + lrow] = v.x;
      aT[(kb + 1) * 68 + lrow] = v.y;
      aT[(kb + 2) * 68 + lrow] = v.z;
      aT[(kb + 3) * 68 + lrow] = v.w;
    }
    const float* cp = Cm + (size_t)lrow * DMODEL + n0 + lseg * 16;
#pragma unroll
    for (int u = 0; u < 4; ++u)
      *(float4*)&bT[lrow * 64 + lseg * 16 + u * 4] = *(const float4*)(cp + u * 4);
  }
  __syncthreads();
  float acc[4][4] = {};
#pragma unroll 16
  for (int kk = 0; kk < 64; ++kk) {
    float4 av = *(const float4*)&aT[kk * 68 + r0];
    float4 bv = *(const float4*)&bT[kk * 64 + c0];
    float ar[4] = {av.x, av.y, av.z, av.w};
    float br[4] = {bv.x, bv.y, bv.z, bv.w};
#pragma unroll
    for (int i = 0; i < 4; ++i)
#pragma unroll
      for (int j = 0; j < 4; ++j) acc[i][j] += ar[i] * br[j];
  }
  const int cg = n0 + c0;
  float4 gv = *(const float4*)&gamma[cg];
  float4 ev = *(const float4*)&beta[cg];
  float4 dv = *(const float4*)&Dv[cg];
#pragma unroll
  for (int i = 0; i < 4; ++i) {
    int m = m0 + r0 + i;
    float4 xv = *(const float4*)&x[(size_t)m * DMODEL + cg];
    float mm = mu[m], rr = rstd[m];
    float o0 = acc[i][0] + ((xv.x - mm) * rr * gv.x + ev.x) * dv.x + xv.x;
    float o1 = acc[i][1] + ((xv.y - mm) * rr * gv.y + ev.y) * dv.y + xv.y;
    float o2 = acc[i][2] + ((xv.z - mm) * rr * gv.z + ev.z) * dv.z + xv.z;
    float o3 = acc[i][3] + ((xv.w - mm) * rr * gv.w + ev.w) * dv.w + xv.w;
    *(float4*)&out[(size_t)m * DMODEL + cg] = make_float4(o0, o1, o2, o3);
  }
}

// ---------- K5: yn = LayerNorm(y) ----------
__global__ void ln_apply_kernel(const float* __restrict__ y, const float* __restrict__ gamma,
                                const float* __restrict__ beta, float* __restrict__ yn) {
  int row = blockIdx.x * 4 + (threadIdx.x >> 6);
  int lane = threadIdx.x & 63;
  const float4* yp = (const float4*)(y + (size_t)row * DMODEL);
  float4 a = yp[lane * 2];
  float4 b = yp[lane * 2 + 1];
  float s = a.x + a.y + a.z + a.w + b.x + b.y + b.z + b.w;
  float q = a.x * a.x + a.y * a.y + a.z * a.z + a.w * a.w + b.x * b.x + b.y * b.y +
            b.z * b.z + b.w * b.w;
  s = wave_sum(s);
  q = wave_sum(q);
  float m = s * (1.0f / DMODEL);
  float var = q * (1.0f / DMODEL) - m * m;
  float rs = rsqrtf(var + LN_EPS);
  const float4* gp = (const float4*)gamma;
  const float4* bp = (const float4*)beta;
  float4 g0 = gp[lane * 2], g1 = gp[lane * 2 + 1];
  float4 e0 = bp[lane * 2], e1 = bp[lane * 2 + 1];
  float4 o0 = make_float4((a.x - m) * rs * g0.x + e0.x, (a.y - m) * rs * g0.y + e0.y,
                          (a.z - m) * rs * g0.z + e0.z, (a.w - m) * rs * g0.w + e0.w);
  float4 o1 = make_float4((b.x - m) * rs * g1.x + e1.x, (b.y - m) * rs * g1.y + e1.y,
                          (b.z - m) * rs * g1.z + e1.z, (b.w - m) * rs * g1.w + e1.w);
  float4* op = (float4*)(yn + (size_t)row * DMODEL);
  op[lane * 2] = o0;
  op[lane * 2 + 1] = o1;
}

// ---------- K6: g = bf16(gelu(yn @ W1 + b1))  [32768,512]x[512,1024] ----------
__global__ __launch_bounds__(256) void mlp1_kernel(const float* __restrict__ yn,
                                                   const float* __restrict__ W1,
                                                   const float* __restrict__ b1,
                                                   unsigned short* __restrict__ g) {
  __shared__ float aT[32 * 68];
  __shared__ float bT[32 * 64];
  const int t = threadIdx.x;
  const int m0 = blockIdx.y * 64;
  const int n0 = blockIdx.x * 64;
  const int ty = t >> 4, tx = t & 15;
  const int r0 = ty * 4, c0 = tx * 4;
  const int lrow = t >> 2, lseg = t & 3;
  const int bk = t >> 3, bseg = t & 7;
  float acc[4][4] = {};
  for (int k0 = 0; k0 < DMODEL; k0 += 32) {
    __syncthreads();
    {
      const float* ap = yn + (size_t)(m0 + lrow) * DMODEL + k0 + lseg * 8;
      float4 v0 = *(const float4*)ap;
      float4 v1 = *(const float4*)(ap + 4);
      const int kb = lseg * 8;
      aT[(kb + 0) * 68 + lrow] = v0.x;
      aT[(kb + 1) * 68 + lrow] = v0.y;
      aT[(kb + 2) * 68 + lrow] = v0.z;
      aT[(kb + 3) * 68 + lrow] = v0.w;
      aT[(kb + 4) * 68 + lrow] = v1.x;
      aT[(kb + 5) * 68 + lrow] = v1.y;
      aT[(kb + 6) * 68 + lrow] = v1.z;
      aT[(kb + 7) * 68 + lrow] = v1.w;
      const float* bp = W1 + (size_t)(k0 + bk) * (2 * DMODEL) + n0 + bseg * 8;
      *(float4*)&bT[bk * 64 + bseg * 8] = *(const float4*)bp;
      *(float4*)&bT[bk * 64 + bseg * 8 + 4] = *(const float4*)(bp + 4);
    }
    __syncthreads();
#pragma unroll
    for (int kk = 0; kk < 32; ++kk) {
      float4 av = *(const float4*)&aT[kk * 68 + r0];
      float4 bv = *(const float4*)&bT[kk * 64 + c0];
      float ar[4] = {av.x, av.y, av.z, av.w};
      float br[4] = {bv.x, bv.y, bv.z, bv.w};
#pragma unroll
      for (int i = 0; i < 4; ++i)
#pragma unroll
        for (int j = 0; j < 4; ++j) acc[i][j] += ar[i] * br[j];
    }
  }
  const int cg = n0 + c0;
  float4 bb = *(const float4*)&b1[cg];
#pragma unroll
  for (int i = 0; i < 4; ++i) {
    ushort4 pk;
    pk.x = f2bf(gelu_exact(acc[i][0] + bb.x));
    pk.y = f2bf(gelu_exact(acc[i][1] + bb.y));
    pk.z = f2bf(gelu_exact(acc[i][2] + bb.z));
    pk.w = f2bf(gelu_exact(acc[i][3] + bb.w));
    *(ushort4*)&g[(size_t)(m0 + r0 + i) * (2 * DMODEL) + cg] = pk;
  }
}

// ---------- K7: out = y + g @ W2 + b2  [32768,1024]x[1024,512] ----------
__global__ __launch_bounds__(256) void mlp2_kernel(const unsigned short* __restrict__ g,
                                                   const float* __restrict__ W2,
                                                   const float* __restrict__ b2,
                                                   float* __restrict__ out) {
  __shared__ float aT[32 * 68];
  __shared__ float bT[32 * 64];
  const int t = threadIdx.x;
  const int m0 = blockIdx.y * 64;
  const int n0 = blockIdx.x * 64;
  const int ty = t >> 4, tx = t & 15;
  const int r0 = ty * 4, c0 = tx * 4;
  const int lrow = t >> 2, lseg = t & 3;
  const int bk = t >> 3, bseg = t & 7;
  float acc[4][4] = {};
  for (int k0 = 0; k0 < 2 * DMODEL; k0 += 32) {
    __syncthreads();
    {
      const unsigned short* gp = g + (size_t)(m0 + lrow) * (2 * DMODEL) + k0 + lseg * 8;
      uint4 v = *(const uint4*)gp;
      const int kb = lseg * 8;
      aT[(kb + 0) * 68 + lrow] = __uint_as_float(v.x << 16);
      aT[(kb + 1) * 68 + lrow] = __uint_as_float(v.x & 0xffff0000u);
      aT[(kb + 2) * 68 + lrow] = __uint_as_float(v.y << 16);
      aT[(kb + 3) * 68 + lrow] = __uint_as_float(v.y & 0xffff0000u);
      aT[(kb + 4) * 68 + lrow] = __uint_as_float(v.z << 16);
      aT[(kb + 5) * 68 + lrow] = __uint_as_float(v.z & 0xffff0000u);
      aT[(kb + 6) * 68 + lrow] = __uint_as_float(v.w << 16);
      aT[(kb + 7) * 68 + lrow] = __uint_as_float(v.w & 0xffff0000u);
      const float* bp = W2 + (size_t)(k0 + bk) * DMODEL + n0 + bseg * 8;
      *(float4*)&bT[bk * 64 + bseg * 8] = *(const float4*)bp;
      *(float4*)&bT[bk * 64 + bseg * 8 + 4] = *(const float4*)(bp + 4);
    }
    __syncthreads();
#pragma unroll
    for (int kk = 0; kk < 32; ++kk) {
      float4 av = *(const float4*)&aT[kk * 68 + r0];
      float4 bv = *(const float4*)&bT[kk * 64 + c0];
      float ar[4] = {av.x, av.y, av.z, av.w};
      float br[4] = {bv.x, bv.y, bv.z, bv.w};
#pragma unroll
      for (int i = 0; i < 4; ++i)
#pragma unroll
        for (int j = 0; j < 4; ++j) acc[i][j] += ar[i] * br[j];
    }
  }
  const int cg = n0 + c0;
  float4 bb = *(const float4*)&b2[cg];
#pragma unroll
  for (int i = 0; i < 4; ++i) {
    size_t off = (size_t)(m0 + r0 + i) * DMODEL + cg;
    float4 yv = *(const float4*)&out[off];
    *(float4*)&out[off] = make_float4(acc[i][0] + bb.x + yv.x, acc[i][1] + bb.y + yv.y,
                                      acc[i][2] + bb.z + yv.z, acc[i][3] + bb.w + yv.w);
  }
}

extern "C" void kernel_launch(void* const* d_in, const int* in_sizes, int n_in, void* d_out,
                              int out_size, void* d_ws, size_t ws_size, hipStream_t stream) {
  const float* x = (const float*)d_in[0];
  const float* logA = (const float*)d_in[1];
  const float* Bm = (const float*)d_in[2];
  const float* Cm = (const float*)d_in[3];
  const float* Dv = (const float*)d_in[4];
  const float* logdt = (const float*)d_in[5];
  const float* gamma = (const float*)d_in[6];
  const float* beta = (const float*)d_in[7];
  const float* W1 = (const float*)d_in[8];
  const float* b1 = (const float*)d_in[9];
  const float* W2 = (const float*)d_in[10];
  const float* b2 = (const float*)d_in[11];
  float* out = (float*)d_out;

  // workspace layout (bytes): total ~136.5 MB
  char* ws = (char*)d_ws;
  float* mu1 = (float*)(ws + 0);                   // 32768 f
  float* rstd1 = (float*)(ws + 131072);            // 32768 f
  float* ends = (float*)(ws + 262144);             // 32768 f
  float* carries = (float*)(ws + 393216);          // 32768 f
  float* xB = (float*)(ws + 524288);               // 8 MB ([B,L,S], becomes hs in-place)
  float* yn = (float*)(ws + 8912896);              // 64 MB
  unsigned short* g = (unsigned short*)(ws + 76021760);  // 64 MB (bf16)

  ln_stats_kernel<<<MROWS / 4, 256, 0, stream>>>(x, mu1, rstd1);
  xb_gemm_kernel<<<MROWS / 64, 256, 0, stream>>>(x, mu1, rstd1, gamma, beta, Bm, xB);
  scan_ends_kernel<<<128, 256, 0, stream>>>(xB, logA, logdt, ends);
  scan_carry_kernel<<<2, 256, 0, stream>>>(ends, logA, logdt, carries);
  scan_fix_kernel<<<128, 256, 0, stream>>>(logA, logdt, carries, xB);
  y_gemm_kernel<<<dim3(DMODEL / 64, MROWS / 64), 256, 0, stream>>>(xB, Cm, x, mu1, rstd1, gamma,
                                                                   beta, Dv, out);
  ln_apply_kernel<<<MROWS / 4, 256, 0, stream>>>(out, gamma, beta, yn);
  mlp1_kernel<<<dim3((2 * DMODEL) / 64, MROWS / 64), 256, 0, stream>>>(yn, W1, b1, g);
  mlp2_kernel<<<dim3(DMODEL / 64, MROWS / 64), 256, 0, stream>>>(g, W2, b2, out);
}

// Round 2
// 368.908 us; speedup vs baseline: 3.0693x; 3.0693x over previous
//
#include <hip/hip_runtime.h>
#include <math.h>

#define BATCH 8
#define SEQL 4096
#define DMODEL 512
#define SDIM 64
#define MROWS (BATCH * SEQL)  // 32768
#define LN_EPS 1e-5f

typedef __attribute__((ext_vector_type(8))) short bf16x8;
typedef __attribute__((ext_vector_type(4))) float f32x4;

// ---------- helpers ----------
__device__ __forceinline__ float wave_sum(float v) {
#pragma unroll
  for (int off = 32; off > 0; off >>= 1) v += __shfl_xor(v, off, 64);
  return v;
}

__device__ __forceinline__ unsigned short f2bf(float f) {  // RNE float->bf16
  unsigned int u = __float_as_uint(f);
  u += 0x7fffu + ((u >> 16) & 1u);
  return (unsigned short)(u >> 16);
}

__device__ __forceinline__ float gelu_exact(float v) {
  return 0.5f * v * (1.0f + erff(v * 0.70710678118654752f));
}

__device__ __forceinline__ void gl2lds16(const void* g, void* l) {
  // async global->LDS, 16B/lane; LDS dest = wave-uniform base + lane*16
  __builtin_amdgcn_global_load_lds((const __attribute__((address_space(1))) void*)g,
                                   (__attribute__((address_space(3))) void*)l, 16, 0, 0);
}

// ---------- K1: LayerNorm stats for x (mu, rstd per row) ----------
__global__ void ln_stats_kernel(const float* __restrict__ x, float* __restrict__ mu,
                                float* __restrict__ rstd) {
  int row = blockIdx.x * 4 + (threadIdx.x >> 6);
  int lane = threadIdx.x & 63;
  const float4* xp = (const float4*)(x + (size_t)row * DMODEL);
  float4 a = xp[lane * 2];
  float4 b = xp[lane * 2 + 1];
  float s = a.x + a.y + a.z + a.w + b.x + b.y + b.z + b.w;
  float q = a.x * a.x + a.y * a.y + a.z * a.z + a.w * a.w + b.x * b.x + b.y * b.y +
            b.z * b.z + b.w * b.w;
  s = wave_sum(s);
  q = wave_sum(q);
  if (lane == 0) {
    float m = s * (1.0f / DMODEL);
    float var = q * (1.0f / DMODEL) - m * m;
    mu[row] = m;
    rstd[row] = rsqrtf(var + LN_EPS);
  }
}

// ---------- K2: xB = LN(x) @ B   [32768,512]x[512,64] -> [B,L,S] ----------
__global__ __launch_bounds__(256) void xb_gemm_kernel(
    const float* __restrict__ x, const float* __restrict__ mu, const float* __restrict__ rstd,
    const float* __restrict__ gamma, const float* __restrict__ beta,
    const float* __restrict__ Bm, float* __restrict__ xB) {
  __shared__ float aT[32 * 68];  // [k][row]
  __shared__ float bT[32 * 64];  // [k][n]
  const int t = threadIdx.x;
  const int m0 = blockIdx.x * 64;
  const int ty = t >> 4, tx = t & 15;
  const int r0 = ty * 4, c0 = tx * 4;
  const int lrow = t >> 2, lseg = t & 3;
  const int bk = t >> 3, bseg = t & 7;
  const float mr = mu[m0 + lrow];
  const float rr = rstd[m0 + lrow];
  float acc[4][4] = {};
  for (int k0 = 0; k0 < DMODEL; k0 += 32) {
    __syncthreads();
    {
      const float* xp = x + (size_t)(m0 + lrow) * DMODEL + k0 + lseg * 8;
      float4 v0 = *(const float4*)xp;
      float4 v1 = *(const float4*)(xp + 4);
      float4 g0 = *(const float4*)(gamma + k0 + lseg * 8);
      float4 g1 = *(const float4*)(gamma + k0 + lseg * 8 + 4);
      float4 e0 = *(const float4*)(beta + k0 + lseg * 8);
      float4 e1 = *(const float4*)(beta + k0 + lseg * 8 + 4);
      const int kb = lseg * 8;
      aT[(kb + 0) * 68 + lrow] = (v0.x - mr) * rr * g0.x + e0.x;
      aT[(kb + 1) * 68 + lrow] = (v0.y - mr) * rr * g0.y + e0.y;
      aT[(kb + 2) * 68 + lrow] = (v0.z - mr) * rr * g0.z + e0.z;
      aT[(kb + 3) * 68 + lrow] = (v0.w - mr) * rr * g0.w + e0.w;
      aT[(kb + 4) * 68 + lrow] = (v1.x - mr) * rr * g1.x + e1.x;
      aT[(kb + 5) * 68 + lrow] = (v1.y - mr) * rr * g1.y + e1.y;
      aT[(kb + 6) * 68 + lrow] = (v1.z - mr) * rr * g1.z + e1.z;
      aT[(kb + 7) * 68 + lrow] = (v1.w - mr) * rr * g1.w + e1.w;
      const float* bp = Bm + (size_t)(k0 + bk) * SDIM + bseg * 8;
      *(float4*)&bT[bk * 64 + bseg * 8] = *(const float4*)bp;
      *(float4*)&bT[bk * 64 + bseg * 8 + 4] = *(const float4*)(bp + 4);
    }
    __syncthreads();
#pragma unroll
    for (int kk = 0; kk < 32; ++kk) {
      float4 av = *(const float4*)&aT[kk * 68 + r0];
      float4 bv = *(const float4*)&bT[kk * 64 + c0];
      float ar[4] = {av.x, av.y, av.z, av.w};
      float br[4] = {bv.x, bv.y, bv.z, bv.w};
#pragma unroll
      for (int i = 0; i < 4; ++i)
#pragma unroll
        for (int j = 0; j < 4; ++j) acc[i][j] += ar[i] * br[j];
    }
  }
#pragma unroll
  for (int i = 0; i < 4; ++i) {
    *(float4*)&xB[(size_t)(m0 + r0 + i) * SDIM + c0] =
        make_float4(acc[i][0], acc[i][1], acc[i][2], acc[i][3]);
  }
}

// ---------- K3a/b/c: exact chunked scan h_t = a*h_{t-1} + x_t over L ----------
__global__ void scan_ends_kernel(const float* __restrict__ xB, const float* __restrict__ logA,
                                 const float* __restrict__ logdt, float* __restrict__ ends) {
  int t = blockIdx.x * 256 + threadIdx.x;
  int s = t & 63;
  int c = (t >> 6) & 63;
  int b = t >> 12;
  float a = expf(-expf(logA[s]) * expf(logdt[0]));
  const float* p = xB + ((size_t)(b * SEQL + c * 64)) * SDIM + s;
  float e = 0.0f;
#pragma unroll
  for (int i = 0; i < 64; ++i) e = a * e + p[(size_t)i * SDIM];
  ends[(b * 64 + c) * 64 + s] = e;
}

__global__ void scan_carry_kernel(const float* __restrict__ ends, const float* __restrict__ logA,
                                  const float* __restrict__ logdt,
                                  float* __restrict__ carries) {
  int t = blockIdx.x * 256 + threadIdx.x;
  int s = t & 63;
  int b = t >> 6;
  float a = expf(-expf(logA[s]) * expf(logdt[0]));
  float a64 = a;
#pragma unroll
  for (int i = 0; i < 6; ++i) a64 *= a64;
  float carry = 0.0f;
  for (int c = 0; c < 64; ++c) {
    carries[(b * 64 + c) * 64 + s] = carry;
    carry = a64 * carry + ends[(b * 64 + c) * 64 + s];
  }
}

__global__ void scan_fix_kernel(const float* __restrict__ logA, const float* __restrict__ logdt,
                                const float* __restrict__ carries, float* __restrict__ xB) {
  int t = blockIdx.x * 256 + threadIdx.x;
  int s = t & 63;
  int c = (t >> 6) & 63;
  int b = t >> 12;
  float a = expf(-expf(logA[s]) * expf(logdt[0]));
  float h = carries[(b * 64 + c) * 64 + s];
  float* p = xB + ((size_t)(b * SEQL + c * 64)) * SDIM + s;
#pragma unroll
  for (int i = 0; i < 64; ++i) {
    h = a * h + p[(size_t)i * SDIM];
    p[(size_t)i * SDIM] = h;
  }
}

// ---------- K4: y = hs @ C + xn*D + x  -> d_out ----------
__global__ __launch_bounds__(256) void y_gemm_kernel(
    const float* __restrict__ hs, const float* __restrict__ Cm, const float* __restrict__ x,
    const float* __restrict__ mu, const float* __restrict__ rstd,
    const float* __restrict__ gamma, const float* __restrict__ beta,
    const float* __restrict__ Dv, float* __restrict__ out) {
  __shared__ float aT[64 * 68];
  __shared__ float bT[64 * 64];
  const int t = threadIdx.x;
  const int m0 = blockIdx.y * 64;
  const int n0 = blockIdx.x * 64;
  const int ty = t >> 4, tx = t & 15;
  const int r0 = ty * 4, c0 = tx * 4;
  const int lrow = t >> 2, lseg = t & 3;
  {
    const float* hp = hs + (size_t)(m0 + lrow) * SDIM + lseg * 16;
#pragma unroll
    for (int u = 0; u < 4; ++u) {
      float4 v = *(const float4*)(hp + u * 4);
      int kb = lseg * 16 + u * 4;
      aT[(kb + 0) * 68 + lrow] = v.x;
      aT[(kb + 1) * 68 + lrow] = v.y;
      aT[(kb + 2) * 68 + lrow] = v.z;
      aT[(kb + 3) * 68 + lrow] = v.w;
    }
    const float* cp = Cm + (size_t)lrow * DMODEL + n0 + lseg * 16;
#pragma unroll
    for (int u = 0; u < 4; ++u)
      *(float4*)&bT[lrow * 64 + lseg * 16 + u * 4] = *(const float4*)(cp + u * 4);
  }
  __syncthreads();
  float acc[4][4] = {};
#pragma unroll 16
  for (int kk = 0; kk < 64; ++kk) {
    float4 av = *(const float4*)&aT[kk * 68 + r0];
    float4 bv = *(const float4*)&bT[kk * 64 + c0];
    float ar[4] = {av.x, av.y, av.z, av.w};
    float br[4] = {bv.x, bv.y, bv.z, bv.w};
#pragma unroll
    for (int i = 0; i < 4; ++i)
#pragma unroll
      for (int j = 0; j < 4; ++j) acc[i][j] += ar[i] * br[j];
  }
  const int cg = n0 + c0;
  float4 gv = *(const float4*)&gamma[cg];
  float4 ev = *(const float4*)&beta[cg];
  float4 dv = *(const float4*)&Dv[cg];
#pragma unroll
  for (int i = 0; i < 4; ++i) {
    int m = m0 + r0 + i;
    float4 xv = *(const float4*)&x[(size_t)m * DMODEL + cg];
    float mm = mu[m], rr = rstd[m];
    float o0 = acc[i][0] + ((xv.x - mm) * rr * gv.x + ev.x) * dv.x + xv.x;
    float o1 = acc[i][1] + ((xv.y - mm) * rr * gv.y + ev.y) * dv.y + xv.y;
    float o2 = acc[i][2] + ((xv.z - mm) * rr * gv.z + ev.z) * dv.z + xv.z;
    float o3 = acc[i][3] + ((xv.w - mm) * rr * gv.w + ev.w) * dv.w + xv.w;
    *(float4*)&out[(size_t)m * DMODEL + cg] = make_float4(o0, o1, o2, o3);
  }
}

// ---------- K5: yn = bf16(LayerNorm(y)) ----------
__global__ void ln_apply_kernel(const float* __restrict__ y, const float* __restrict__ gamma,
                                const float* __restrict__ beta,
                                unsigned short* __restrict__ yn) {
  int row = blockIdx.x * 4 + (threadIdx.x >> 6);
  int lane = threadIdx.x & 63;
  const float4* yp = (const float4*)(y + (size_t)row * DMODEL);
  float4 a = yp[lane * 2];
  float4 b = yp[lane * 2 + 1];
  float s = a.x + a.y + a.z + a.w + b.x + b.y + b.z + b.w;
  float q = a.x * a.x + a.y * a.y + a.z * a.z + a.w * a.w + b.x * b.x + b.y * b.y +
            b.z * b.z + b.w * b.w;
  s = wave_sum(s);
  q = wave_sum(q);
  float m = s * (1.0f / DMODEL);
  float var = q * (1.0f / DMODEL) - m * m;
  float rs = rsqrtf(var + LN_EPS);
  const float4* gp = (const float4*)gamma;
  const float4* bp = (const float4*)beta;
  float4 g0 = gp[lane * 2], g1 = gp[lane * 2 + 1];
  float4 e0 = bp[lane * 2], e1 = bp[lane * 2 + 1];
  float o0x = (a.x - m) * rs * g0.x + e0.x, o0y = (a.y - m) * rs * g0.y + e0.y;
  float o0z = (a.z - m) * rs * g0.z + e0.z, o0w = (a.w - m) * rs * g0.w + e0.w;
  float o1x = (b.x - m) * rs * g1.x + e1.x, o1y = (b.y - m) * rs * g1.y + e1.y;
  float o1z = (b.z - m) * rs * g1.z + e1.z, o1w = (b.w - m) * rs * g1.w + e1.w;
  uint4 pk;
  pk.x = (unsigned)f2bf(o0x) | ((unsigned)f2bf(o0y) << 16);
  pk.y = (unsigned)f2bf(o0z) | ((unsigned)f2bf(o0w) << 16);
  pk.z = (unsigned)f2bf(o1x) | ((unsigned)f2bf(o1y) << 16);
  pk.w = (unsigned)f2bf(o1z) | ((unsigned)f2bf(o1w) << 16);
  ((uint4*)(yn + (size_t)row * DMODEL))[lane] = pk;
}

// ---------- transpose+convert: W [K][N] f32 -> Wt [N][K] bf16 ----------
__global__ __launch_bounds__(256) void transpose_bf16_kernel(const float* __restrict__ W,
                                                             unsigned short* __restrict__ Wt,
                                                             int K, int N) {
  __shared__ unsigned short tile[64][65];
  int k0 = blockIdx.y * 64, n0 = blockIdx.x * 64;
  int tx = threadIdx.x & 15, ty = threadIdx.x >> 4;
#pragma unroll
  for (int p = 0; p < 4; ++p) {
    int k = p * 16 + ty;
    float4 v = *(const float4*)&W[(size_t)(k0 + k) * N + n0 + tx * 4];
    tile[tx * 4 + 0][k] = f2bf(v.x);
    tile[tx * 4 + 1][k] = f2bf(v.y);
    tile[tx * 4 + 2][k] = f2bf(v.z);
    tile[tx * 4 + 3][k] = f2bf(v.w);
  }
  __syncthreads();
#pragma unroll
  for (int p = 0; p < 4; ++p) {
    int n = p * 16 + ty;
    ushort4 o;
    o.x = tile[n][tx * 4 + 0];
    o.y = tile[n][tx * 4 + 1];
    o.z = tile[n][tx * 4 + 2];
    o.w = tile[n][tx * 4 + 3];
    *(ushort4*)&Wt[(size_t)(n0 + n) * K + k0 + tx * 4] = o;
  }
}

// ---------- MFMA MLP GEMM 1: g = bf16(gelu(yn @ W1 + b1)) ----------
// yn: [M][512] bf16 row-major; w1t: [1024][512] bf16 (N-major); g: [M][1024] bf16
__global__ __launch_bounds__(256) void mlp1_mfma_kernel(const unsigned short* __restrict__ yn,
                                                        const unsigned short* __restrict__ w1t,
                                                        const float* __restrict__ b1,
                                                        unsigned short* __restrict__ g) {
  __shared__ unsigned short As[128 * 32];  // [m][k], unpadded (global_load_lds layout)
  __shared__ unsigned short Bs[128 * 32];  // [n][k]
  const int t = threadIdx.x;
  const int wave = t >> 6, lane = t & 63;
  const int m0 = blockIdx.y * 128, n0 = blockIdx.x * 128;
  const int wm = (wave >> 1) * 64, wn = (wave & 1) * 64;
  const int row0 = t >> 2, seg0 = t & 3;            // chunk t
  const int row1 = (t + 256) >> 2, seg1 = t & 3;    // chunk t+256
  const unsigned short* gA0 = yn + (size_t)(m0 + row0) * 512 + seg0 * 8;
  const unsigned short* gA1 = yn + (size_t)(m0 + row1) * 512 + seg1 * 8;
  const unsigned short* gB0 = w1t + (size_t)(n0 + row0) * 512 + seg0 * 8;
  const unsigned short* gB1 = w1t + (size_t)(n0 + row1) * 512 + seg1 * 8;
  unsigned short* lA0 = As + (size_t)(wave * 64) * 8;
  unsigned short* lA1 = As + (size_t)(256 + wave * 64) * 8;
  unsigned short* lB0 = Bs + (size_t)(wave * 64) * 8;
  unsigned short* lB1 = Bs + (size_t)(256 + wave * 64) * 8;
  f32x4 acc[4][4] = {};
  const int fr = lane & 15, fq = lane >> 4;  // fragment row/col, k-quad
  for (int k0 = 0; k0 < 512; k0 += 32) {
    __syncthreads();
    gl2lds16(gA0 + k0, lA0);
    gl2lds16(gA1 + k0, lA1);
    gl2lds16(gB0 + k0, lB0);
    gl2lds16(gB1 + k0, lB1);
    __syncthreads();
#pragma unroll
    for (int i = 0; i < 4; ++i) {
      bf16x8 a = *(const bf16x8*)&As[(wm + i * 16 + fr) * 32 + fq * 8];
#pragma unroll
      for (int j = 0; j < 4; ++j) {
        bf16x8 b = *(const bf16x8*)&Bs[(wn + j * 16 + fr) * 32 + fq * 8];
        acc[i][j] = __builtin_amdgcn_mfma_f32_16x16x32_bf16(a, b, acc[i][j], 0, 0, 0);
      }
    }
  }
#pragma unroll
  for (int i = 0; i < 4; ++i)
#pragma unroll
    for (int j = 0; j < 4; ++j) {
      const int cg = n0 + wn + j * 16 + fr;
      const float bb = b1[cg];
#pragma unroll
      for (int r = 0; r < 4; ++r) {
        const int rg = m0 + wm + i * 16 + fq * 4 + r;
        g[(size_t)rg * 1024 + cg] = f2bf(gelu_exact(acc[i][j][r] + bb));
      }
    }
}

// ---------- MFMA MLP GEMM 2: out = y + g @ W2 + b2 ----------
// g: [M][1024] bf16; w2t: [512][1024] bf16; out: [M][512] f32 (holds y, RMW)
__global__ __launch_bounds__(256) void mlp2_mfma_kernel(const unsigned short* __restrict__ g,
                                                        const unsigned short* __restrict__ w2t,
                                                        const float* __restrict__ b2,
                                                        float* __restrict__ out) {
  __shared__ unsigned short As[128 * 32];
  __shared__ unsigned short Bs[128 * 32];
  const int t = threadIdx.x;
  const int wave = t >> 6, lane = t & 63;
  const int m0 = blockIdx.y * 128, n0 = blockIdx.x * 128;
  const int wm = (wave >> 1) * 64, wn = (wave & 1) * 64;
  const int row0 = t >> 2, seg0 = t & 3;
  const int row1 = (t + 256) >> 2, seg1 = t & 3;
  const unsigned short* gA0 = g + (size_t)(m0 + row0) * 1024 + seg0 * 8;
  const unsigned short* gA1 = g + (size_t)(m0 + row1) * 1024 + seg1 * 8;
  const unsigned short* gB0 = w2t + (size_t)(n0 + row0) * 1024 + seg0 * 8;
  const unsigned short* gB1 = w2t + (size_t)(n0 + row1) * 1024 + seg1 * 8;
  unsigned short* lA0 = As + (size_t)(wave * 64) * 8;
  unsigned short* lA1 = As + (size_t)(256 + wave * 64) * 8;
  unsigned short* lB0 = Bs + (size_t)(wave * 64) * 8;
  unsigned short* lB1 = Bs + (size_t)(256 + wave * 64) * 8;
  f32x4 acc[4][4] = {};
  const int fr = lane & 15, fq = lane >> 4;
  for (int k0 = 0; k0 < 1024; k0 += 32) {
    __syncthreads();
    gl2lds16(gA0 + k0, lA0);
    gl2lds16(gA1 + k0, lA1);
    gl2lds16(gB0 + k0, lB0);
    gl2lds16(gB1 + k0, lB1);
    __syncthreads();
#pragma unroll
    for (int i = 0; i < 4; ++i) {
      bf16x8 a = *(const bf16x8*)&As[(wm + i * 16 + fr) * 32 + fq * 8];
#pragma unroll
      for (int j = 0; j < 4; ++j) {
        bf16x8 b = *(const bf16x8*)&Bs[(wn + j * 16 + fr) * 32 + fq * 8];
        acc[i][j] = __builtin_amdgcn_mfma_f32_16x16x32_bf16(a, b, acc[i][j], 0, 0, 0);
      }
    }
  }
#pragma unroll
  for (int i = 0; i < 4; ++i)
#pragma unroll
    for (int j = 0; j < 4; ++j) {
      const int cg = n0 + wn + j * 16 + fr;
      const float bb = b2[cg];
#pragma unroll
      for (int r = 0; r < 4; ++r) {
        const int rg = m0 + wm + i * 16 + fq * 4 + r;
        const size_t off = (size_t)rg * 512 + cg;
        out[off] = out[off] + acc[i][j][r] + bb;
      }
    }
}

extern "C" void kernel_launch(void* const* d_in, const int* in_sizes, int n_in, void* d_out,
                              int out_size, void* d_ws, size_t ws_size, hipStream_t stream) {
  const float* x = (const float*)d_in[0];
  const float* logA = (const float*)d_in[1];
  const float* Bm = (const float*)d_in[2];
  const float* Cm = (const float*)d_in[3];
  const float* Dv = (const float*)d_in[4];
  const float* logdt = (const float*)d_in[5];
  const float* gamma = (const float*)d_in[6];
  const float* beta = (const float*)d_in[7];
  const float* W1 = (const float*)d_in[8];
  const float* b1 = (const float*)d_in[9];
  const float* W2 = (const float*)d_in[10];
  const float* b2 = (const float*)d_in[11];
  float* out = (float*)d_out;

  // workspace layout (bytes): total ~106.5 MB
  char* ws = (char*)d_ws;
  float* mu1 = (float*)(ws + 0);                       // 128 KB
  float* rstd1 = (float*)(ws + 131072);                // 128 KB
  float* ends = (float*)(ws + 262144);                 // 128 KB
  float* carries = (float*)(ws + 393216);              // 128 KB
  float* xB = (float*)(ws + 524288);                   // 8 MB ([B,L,S] -> hs in-place)
  unsigned short* yn = (unsigned short*)(ws + 8912896);    // 32 MB bf16
  unsigned short* g = (unsigned short*)(ws + 42467328);    // 64 MB bf16
  unsigned short* w1t = (unsigned short*)(ws + 109576192); // 1 MB bf16 [1024][512]
  unsigned short* w2t = (unsigned short*)(ws + 110624768); // 1 MB bf16 [512][1024]

  // weight transposes (no deps on x; cheap)
  transpose_bf16_kernel<<<dim3(1024 / 64, 512 / 64), 256, 0, stream>>>(W1, w1t, 512, 1024);
  transpose_bf16_kernel<<<dim3(512 / 64, 1024 / 64), 256, 0, stream>>>(W2, w2t, 1024, 512);

  ln_stats_kernel<<<MROWS / 4, 256, 0, stream>>>(x, mu1, rstd1);
  xb_gemm_kernel<<<MROWS / 64, 256, 0, stream>>>(x, mu1, rstd1, gamma, beta, Bm, xB);
  scan_ends_kernel<<<128, 256, 0, stream>>>(xB, logA, logdt, ends);
  scan_carry_kernel<<<2, 256, 0, stream>>>(ends, logA, logdt, carries);
  scan_fix_kernel<<<128, 256, 0, stream>>>(logA, logdt, carries, xB);
  y_gemm_kernel<<<dim3(DMODEL / 64, MROWS / 64), 256, 0, stream>>>(xB, Cm, x, mu1, rstd1, gamma,
                                                                   beta, Dv, out);
  ln_apply_kernel<<<MROWS / 4, 256, 0, stream>>>(out, gamma, beta, yn);
  mlp1_mfma_kernel<<<dim3(1024 / 128, MROWS / 128), 256, 0, stream>>>(yn, w1t, b1, g);
  mlp2_mfma_kernel<<<dim3(512 / 128, MROWS / 128), 256, 0, stream>>>(g, w2t, b2, out);
}